// Round 6
// baseline (192.850 us; speedup 1.0000x reference)
//
#include <hip/hip_runtime.h>

#define KDIM 4096
#define NDIM 4096
#define BM 256
#define BN 256
#define BK 128            // K bytes (int8) per tile
#define NTILE (KDIM / BK) // 32

using i32x4 = __attribute__((ext_vector_type(4))) int;
using i32x16 = __attribute__((ext_vector_type(16))) int;

__device__ __forceinline__ void g2l16(const void* g, void* l) {
  __builtin_amdgcn_global_load_lds(
      (const __attribute__((address_space(1))) void*)g,
      (__attribute__((address_space(3))) void*)l,
      16, 0, 0);
}

// ---------------- detect: weight buffer int32-expanded (flag=1) or raw int8 (flag=0)?
__global__ void w8l_detect(const int* __restrict__ w32, int* __restrict__ flag) {
  __shared__ int s;
  const int t = threadIdx.x;
  if (t == 0) s = 1;
  __syncthreads();
  bool oob = false;
#pragma unroll
  for (int i = 0; i < 16; ++i) {
    int v = w32[t * 16 + i];
    if (v < -128 || v > 127) oob = true;
  }
  if (oob) atomicAnd(&s, 0);
  __syncthreads();
  if (t == 0) *flag = s;
}

// ---------------- pack int32 weights to int8 (no-op when flag==0)
__global__ void w8l_pack(const void* __restrict__ wsrc, const int* __restrict__ flag,
                         signed char* __restrict__ wq) {
  if (*flag == 0) return;
  const int t = blockIdx.x * blockDim.x + threadIdx.x;
  const int4* s = (const int4*)wsrc;
  int4 a = s[t * 4 + 0], b = s[t * 4 + 1], c = s[t * 4 + 2], d = s[t * 4 + 3];
  int4 o;
  o.x = (a.x & 255) | ((a.y & 255) << 8) | ((a.z & 255) << 16) | ((a.w & 255) << 24);
  o.y = (b.x & 255) | ((b.y & 255) << 8) | ((b.z & 255) << 16) | ((b.w & 255) << 24);
  o.z = (c.x & 255) | ((c.y & 255) << 8) | ((c.z & 255) << 16) | ((c.w & 255) << 24);
  o.w = (d.x & 255) | ((d.y & 255) << 8) | ((d.z & 255) << 16) | ((d.w & 255) << 24);
  ((int4*)wq)[t] = o;
}

// ---------------- quantize activations: 16 floats / thread
__global__ void w8l_quant(const float* __restrict__ x, const float* __restrict__ xs,
                          signed char* __restrict__ xq) {
  const int t = blockIdx.x * blockDim.x + threadIdx.x;
  const float s = *xs;
  const float4* x4 = (const float4*)x;
  int4 o;
  int* op = (int*)&o;
#pragma unroll
  for (int q = 0; q < 4; ++q) {
    float4 f = x4[t * 4 + q];
    int v0 = __float2int_rn(f.x / s);
    int v1 = __float2int_rn(f.y / s);
    int v2 = __float2int_rn(f.z / s);
    int v3 = __float2int_rn(f.w / s);
    v0 = v0 < -128 ? -128 : (v0 > 127 ? 127 : v0);
    v1 = v1 < -128 ? -128 : (v1 > 127 ? 127 : v1);
    v2 = v2 < -128 ? -128 : (v2 > 127 ? 127 : v2);
    v3 = v3 < -128 ? -128 : (v3 > 127 ? 127 : v3);
    op[q] = (v0 & 255) | ((v1 & 255) << 8) | ((v2 & 255) << 16) | ((v3 & 255) << 24);
  }
  ((int4*)xq)[t] = o;
}

// ---------------- 256x256 i8 GEMM, 32x32x32 MFMA, per-kstep register pipeline.
// 4 ksteps/K-tile; each step issues the NEXT step's 6 ds_read_b128 then runs
// its 8-MFMA cluster (compiler places the exact lgkmcnt). One lgkm(0)+vmcnt(0)
// +barrier per K-tile at the boundary only.
// LDS buffer b: A at b*65536, B at +32768; row = 128 B = 8 slots of 16 B;
// LDS(r,slot) holds global k-chunk (slot ^ (r&7)) (rule #21 construction).
__global__ __launch_bounds__(512, 2) void w8l_gemm32(
    const signed char* __restrict__ Aq,
    const signed char* __restrict__ Wraw, const signed char* __restrict__ Wpk,
    const int* __restrict__ flag,
    const float* __restrict__ scale, const float* __restrict__ xscale,
    const float* __restrict__ bias, float* __restrict__ out, int nbn) {
  __shared__ signed char lds[131072];

  const signed char* __restrict__ Wq = (*flag) ? Wpk : Wraw;

  const int tid = threadIdx.x;
  const int lane = tid & 63;
  const int wid = tid >> 6;  // 0..7
  const int wr = wid >> 2;   // 0..1 (wave tile: 128 rows)
  const int wc = wid & 3;    // 0..3 (wave tile: 64 cols)
  const int l31 = lane & 31;
  const int l5 = lane >> 5;  // 0..1 : k-halfgroup

  // XCD-aware bijective swizzle (grid = 512, divisible by 8)
  const int nwg = gridDim.x;
  const int cpx = nwg >> 3;
  const int bid = blockIdx.x;
  const int swz = (bid & 7) * cpx + (bid >> 3);
  const int bm = swz / nbn, bn = swz % nbn;
  const int m0 = bm * BM, n0 = bn * BN;

  // staging: one g2l16 issue moves 8 KB (64 rows x 128 B) across 512 threads
  const unsigned lin = (unsigned)tid * 16u;
  const unsigned r_in = lin >> 7;  // 0..63
  const unsigned c16 = (lin >> 4) & 7;
  const unsigned swcol = ((c16 ^ (r_in & 7)) << 4);
  const signed char* agp = Aq + (size_t)(m0 + r_in) * KDIM + swcol;
  const signed char* wgp = Wq + (size_t)(n0 + r_in) * KDIM + swcol;
  const unsigned ldsoff_thr = r_in * 128u + c16 * 16u;

#define ISSUE_TILE(t)                                                       \
  do {                                                                      \
    const int t_ = (t);                                                     \
    const size_t koff_ = (size_t)t_ * BK;                                   \
    signed char* lb_ = lds + (unsigned)(t_ & 1) * 65536u + ldsoff_thr;      \
    _Pragma("unroll") for (int u = 0; u < 4; ++u)                           \
      g2l16(agp + (size_t)(u * 64) * KDIM + koff_, lb_ + u * 8192);         \
    _Pragma("unroll") for (int u = 0; u < 4; ++u)                           \
      g2l16(wgp + (size_t)(u * 64) * KDIM + koff_, lb_ + 32768 + u * 8192); \
  } while (0)

  // 32x32x32 fragment: lane holds row (l&31), 16 B at k-chunk (ks*2 + l>>5)
#define RD_AB(av, bv, Ab, Bb, ks)                                            \
  do {                                                                       \
    _Pragma("unroll") for (int mi = 0; mi < 4; ++mi) {                       \
      const int r_ = wr * 128 + mi * 32 + l31;                               \
      av[mi] = *(const i32x4*)((Ab) + r_ * 128 +                             \
                               ((((ks) * 2 + l5) ^ (r_ & 7)) << 4));         \
    }                                                                        \
    _Pragma("unroll") for (int nj = 0; nj < 2; ++nj) {                       \
      const int r_ = wc * 64 + nj * 32 + l31;                                \
      bv[nj] = *(const i32x4*)((Bb) + r_ * 128 +                             \
                               ((((ks) * 2 + l5) ^ (r_ & 7)) << 4));         \
    }                                                                        \
  } while (0)

#define CLUSTER(av, bv)                                                      \
  __builtin_amdgcn_s_setprio(1);                                             \
  _Pragma("unroll") for (int mi = 0; mi < 4; ++mi)                           \
      _Pragma("unroll") for (int nj = 0; nj < 2; ++nj)                       \
          acc[mi][nj] = __builtin_amdgcn_mfma_i32_32x32x32_i8(               \
              av[mi], bv[nj], acc[mi][nj], 0, 0, 0);                         \
  __builtin_amdgcn_s_setprio(0);

  i32x16 acc[4][2] = {};
  i32x4 aE[4], bE[2], aO[4], bO[2];

  // prologue: 2 tiles (16 g2l) in flight; vmcnt(8) = tile0's 8 landed,
  // tile1's 8 still outstanding.  (r5 bug: vmcnt(16) was a no-op -> race)
  ISSUE_TILE(0);
  ISSUE_TILE(1);
  asm volatile("s_waitcnt vmcnt(8)" ::: "memory");
  __builtin_amdgcn_s_barrier();
  __builtin_amdgcn_sched_barrier(0);
  RD_AB(aE, bE, lds, lds + 32768, 0);
  __builtin_amdgcn_sched_barrier(0);

#pragma unroll 1
  for (int kt = 0; kt < NTILE; ++kt) {
    const signed char* Ab = lds + (kt & 1) * 65536;
    const signed char* Bb = Ab + 32768;

    // step0: issue ks1 reads, MFMA ks0
    RD_AB(aO, bO, Ab, Bb, 1);
    __builtin_amdgcn_sched_barrier(0);
    CLUSTER(aE, bE);
    __builtin_amdgcn_sched_barrier(0);
    // step1: issue ks2 reads, MFMA ks1
    RD_AB(aE, bE, Ab, Bb, 2);
    __builtin_amdgcn_sched_barrier(0);
    CLUSTER(aO, bO);
    __builtin_amdgcn_sched_barrier(0);
    // step2: issue ks3 reads, MFMA ks2
    RD_AB(aO, bO, Ab, Bb, 3);
    __builtin_amdgcn_sched_barrier(0);
    CLUSTER(aE, bE);
    __builtin_amdgcn_sched_barrier(0);
    // step3 + boundary: drain own reads (WAR), landed prefetch, barrier,
    // stage kt+2, read next tile ks0 under the ks3 cluster
    if (kt + 1 < NTILE) {
      asm volatile("s_waitcnt lgkmcnt(0)" ::: "memory");
      __builtin_amdgcn_sched_barrier(0);
      asm volatile("s_waitcnt vmcnt(0)" ::: "memory");
      __builtin_amdgcn_s_barrier();
      __builtin_amdgcn_sched_barrier(0);
      if (kt + 2 < NTILE) ISSUE_TILE(kt + 2);
      const signed char* An = lds + ((kt + 1) & 1) * 65536;
      RD_AB(aE, bE, An, An + 32768, 0);
      __builtin_amdgcn_sched_barrier(0);
    }
    CLUSTER(aO, bO);
    __builtin_amdgcn_sched_barrier(0);
  }

  // epilogue: 32x32 C/D layout col=lane&31, row=(reg&3)+8*(reg>>2)+4*(lane>>5)
  // [m74/m101-verified, dtype-independent]
  const float cs = scale[0] * xscale[0];
#pragma unroll
  for (int nj = 0; nj < 2; ++nj) {
    const int n = n0 + wc * 64 + nj * 32 + l31;
    const float bj = bias[n];
#pragma unroll
    for (int mi = 0; mi < 4; ++mi) {
      const int mbase = m0 + wr * 128 + mi * 32 + l5 * 4;
#pragma unroll
      for (int r = 0; r < 16; ++r) {
        const int m = mbase + (r & 3) + 8 * (r >> 2);
        out[(size_t)m * NDIM + n] = (float)acc[mi][nj][r] * cs + bj;
      }
    }
  }
#undef ISSUE_TILE
#undef RD_AB
#undef CLUSTER
}

extern "C" void kernel_launch(void* const* d_in, const int* in_sizes, int n_in,
                              void* d_out, int out_size, void* d_ws, size_t ws_size,
                              hipStream_t stream) {
  const float* x = (const float*)d_in[0];
  const void* w = d_in[1];
  const float* scale = (const float*)d_in[2];
  const float* xscale = (const float*)d_in[3];
  const float* bias = (const float*)d_in[4];
  float* out = (float*)d_out;

  const int M = in_sizes[0] / KDIM;  // 8192

  int* flag = (int*)d_ws;
  signed char* wq = (signed char*)d_ws + 256;
  signed char* aq = wq + (size_t)NDIM * KDIM;

  const size_t need = 256 + (size_t)NDIM * KDIM + (size_t)M * KDIM;
  if (ws_size < need) return;

  w8l_detect<<<1, 256, 0, stream>>>((const int*)w, flag);
  w8l_pack<<<(NDIM * KDIM / 16) / 256, 256, 0, stream>>>(w, flag, wq);
  w8l_quant<<<(M * KDIM / 16) / 256, 256, 0, stream>>>(x, xscale, aq);

  const int nbn = NDIM / BN;  // 16
  w8l_gemm32<<<(M / BM) * nbn, 512, 0, stream>>>(
      aq, (const signed char*)w, wq, flag, scale, xscale, bias, out, nbn);
}